// Round 20
// baseline (169.938 us; speedup 1.0000x reference)
//
#include <hip/hip_runtime.h>
#include <hip/hip_bf16.h>
#include <hip/hip_fp16.h>
#include <math.h>

#define NN    8192
#define TT    64
#define DIN   64
#define RR    256
#define DOUT  64
#define HID   128
#define CATD  1024
#define NE    131072
#define MASKW 256              // 8192 bits / 32
#define MAXD  256              // neighbor list capacity (avg deg ~32)
#define HROW  328              // shorts/node-row: 320 data (40 16B-slots) + 8 pad
#define C8ROW 768              // fp8 shadow row: 3 slices x 256 bytes
#define L2E2  2.8853900817779268f   // 2*log2(e), folded into W_aug at setup

typedef __attribute__((ext_vector_type(8))) short    s16x8;   // 8 bf16 bits
typedef __attribute__((ext_vector_type(8))) _Float16 f16x8;   // 8 fp16
typedef __attribute__((ext_vector_type(4))) float    f32x4;
typedef __attribute__((ext_vector_type(2))) float    f32x2;

static __device__ __forceinline__ unsigned short f2bs(float f) {
  union { __hip_bfloat16 b; unsigned short u; } cv;
  cv.b = __float2bfloat16(f);
  return cv.u;
}
static __device__ __forceinline__ unsigned int pack2bf(float a, float b) {
  return (unsigned int)f2bs(a) | ((unsigned int)f2bs(b) << 16);
}
// 1-inst packed f32->bf16 (RNE); safe for finite inputs (tanh outputs, x values)
static __device__ __forceinline__ unsigned int cvtpk2bf(float a, float b) {
  unsigned int r;
  asm("v_cvt_pk_bf16_f32 %0, %1, %2" : "=v"(r) : "v"(a), "v"(b));
  return r;
}
static __device__ __forceinline__ unsigned int pack2h(float a, float b) {
  return (unsigned int)__half_as_ushort(__float2half(a))
       | ((unsigned int)__half_as_ushort(__float2half(b)) << 16);
}
static __device__ __forceinline__ unsigned int pack4fp8(float a, float b, float c, float d) {
  unsigned int p = 0;
  p = __builtin_amdgcn_cvt_pk_fp8_f32(a, b, (int)p, false);   // bytes 0,1
  p = __builtin_amdgcn_cvt_pk_fp8_f32(c, d, (int)p, true);    // bytes 2,3
  return p;
}

// ---------------- setup kernels ----------------

// fused: zero adjacency mask + one-shot weight conversion
// W_res/W_in are pre-scaled by 2*log2(e) so the esn tanh needs no pre-multiply.
__global__ __launch_bounds__(256) void setup_kernel(
    uint4* __restrict__ mask4,
    const float* __restrict__ Wres, const float* __restrict__ Win,
    const float* __restrict__ W1, const float* __restrict__ W2,
    unsigned short* __restrict__ wresh, unsigned short* __restrict__ winh,
    unsigned short* __restrict__ W1h, unsigned short* __restrict__ W2h) {
  int i = blockIdx.x * 256 + threadIdx.x;
  mask4[i] = make_uint4(0u, 0u, 0u, 0u);       // grid exactly covers 8 MB / 16 B
  if (i < 65536) wresh[i] = f2bs(Wres[i] * L2E2);
  else if (i < 81920) winh[i - 65536] = f2bs(Win[i - 65536] * L2E2);
  else if (i < 212992) W1h[i - 81920] = __half_as_ushort(__float2half(W1[i - 81920]));
  else if (i < 221184) W2h[i - 212992] = __half_as_ushort(__float2half(W2[i - 212992]));
}

__global__ __launch_bounds__(256) void edge_kernel(const int* __restrict__ eidx,
                                                   unsigned int* __restrict__ mask) {
  int e = blockIdx.x * 256 + threadIdx.x;
  if (e < NE) {
    int u = eidx[e];
    int v = eidx[NE + e];
    atomicOr(&mask[(size_t)u * MASKW + (v >> 5)], 1u << (v & 31));
    atomicOr(&mask[(size_t)v * MASKW + (u >> 5)], 1u << (u & 31));
  }
}

// neighbor list via prefix scan over mask words; also emits dinv
__global__ __launch_bounds__(256) void nbrlist_kernel(const unsigned int* __restrict__ mask,
                                                      unsigned short* __restrict__ nbrlist,
                                                      int* __restrict__ nbrcnt,
                                                      float* __restrict__ dinv) {
  __shared__ int wsum[4];
  const int n = blockIdx.x;
  const int tid = threadIdx.x;
  const int lane = tid & 63;
  const int w = tid >> 6;
  unsigned int m = mask[(size_t)n * MASKW + tid];
  const int c = __popc(m);
  int inc = c;
#pragma unroll
  for (int d = 1; d < 64; d <<= 1) {
    int v = __shfl_up(inc, d, 64);
    if (lane >= d) inc += v;
  }
  if (lane == 63) wsum[w] = inc;
  __syncthreads();
  int base = 0;
  for (int i = 0; i < w; ++i) base += wsum[i];
  int off = base + inc - c;     // exclusive prefix
  while (m) {
    int b = __ffs(m) - 1;
    m &= m - 1;
    if (off < MAXD) nbrlist[(size_t)n * MAXD + off] = (unsigned short)(tid * 32 + b);
    ++off;
  }
  if (tid == 255) {
    int tot = base + inc;
    nbrcnt[n] = tot < MAXD ? tot : MAXD;
    dinv[n] = (tot > 0) ? fminf(rsqrtf((float)tot), 1e6f) : 0.0f;
  }
}

// ---------------- ESN via bf16 MFMA, augmented K=320 ----------------
// Block: 512 threads = 8 waves, 16 nodes. Wave w owns r in [w*32, w*32+32) (2 rtiles).
// A = W_aug rows (stationary, pre-scaled by 2*log2e), B = [h ; x_t] from LDS.
// Loop-invariant addressing, t-loop unrolled x2 for buffer ping-pong.
// 4 accumulation chains (even/odd K) to halve MFMA dependency depth.
__global__ __launch_bounds__(512, 4) void esn_mfma_kernel(
    const float* __restrict__ x,               // [N][T][DIN] fp32
    const unsigned short* __restrict__ winh,   // [R][DIN] bf16 (pre-scaled)
    const unsigned short* __restrict__ wresh,  // [R][R]   bf16 (pre-scaled)
    unsigned short* __restrict__ cat,          // [N][CATD] fp16, writes cols 0..255
    unsigned char* __restrict__ cat8)          // [N][768] fp8 shadow, writes slice 0
{
  __shared__ unsigned short hs[2][16][HROW];   // [buf][node][k: 0..255 h, 256..319 x]
  const int tid  = threadIdx.x;
  const int lane = tid & 63;
  const int w    = tid >> 6;     // wave 0..7
  const int lr   = lane & 15;    // node (B col / D col)
  const int lg   = lane >> 4;    // k-group / row-group
  const int sn   = tid >> 5;     // staging: node 0..15
  const int sq   = tid & 31;     // staging: float2 index 0..31 (d = sq*2)
  const long gn0 = (long)blockIdx.x * 16;
  const int bx   = (lr >> 3) & 1;
  const int lgx  = lg ^ bx;              // read swizzle folded
  const int lgw  = (lg >> 1) ^ bx;       // write swizzle folded
  const int bs   = (sn >> 3) & 1;

  // stationary A-fragments: W_aug = [W_res | W_in], 2 rtiles x 10 ktiles
  s16x8 waug[2][10];
#pragma unroll
  for (int rt = 0; rt < 2; ++rt) {
    const int r = w * 32 + rt * 16 + lr;
#pragma unroll
    for (int kt = 0; kt < 8; ++kt)
      waug[rt][kt] = *(const s16x8*)(wresh + r * RR + kt * 32 + lg * 8);
#pragma unroll
    for (int kt = 8; kt < 10; ++kt)
      waug[rt][kt] = *(const s16x8*)(winh + r * DIN + (kt - 8) * 32 + lg * 8);
  }

  // loop-invariant LDS addresses (shorts)
  unsigned short* const rd0 = &hs[0][0][0] + lr * HROW + lgx * 8;  // + kt*32
  unsigned short* const rd1 = &hs[1][0][0] + lr * HROW + lgx * 8;
  unsigned short* const wh0 = &hs[0][0][0] + lr * HROW + (w * 4 + lgw) * 8 + (lg & 1) * 4;  // + rt*16
  unsigned short* const wh1 = &hs[1][0][0] + lr * HROW + (w * 4 + lgw) * 8 + (lg & 1) * 4;
  unsigned short* const xs0 = &hs[0][0][0] + sn * HROW + (32 + ((sq >> 2) ^ bs)) * 8 + (sq & 3) * 2;
  unsigned short* const xs1 = &hs[1][0][0] + sn * HROW + (32 + ((sq >> 2) ^ bs)) * 8 + (sq & 3) * 2;

  // zero buffer 0
  for (int i = tid; i < 16 * HROW / 2; i += 512) ((unsigned int*)hs[0])[i] = 0u;

  // rolling x prefetch: thread (sn, sq) loads float2
  const float* xrow = x + (gn0 + sn) * (long)(TT * DIN) + sq * 2;
  float2 xr0 = *(const float2*)(xrow);            // t=0
  float2 xr1 = *(const float2*)(xrow + DIN);      // t=1
  __syncthreads();                                // zeroing done
  *(unsigned int*)xs0 = cvtpk2bf(xr0.x, xr0.y);   // stage x_0 -> buf0
  xr0 = *(const float2*)(xrow + 2 * DIN);         // t=2

  f32x4 hreg[2];
  hreg[0] = (f32x4){0.f, 0.f, 0.f, 0.f};
  hreg[1] = (f32x4){0.f, 0.f, 0.f, 0.f};
  __syncthreads();

#define ESN_STEP(RD, WH, XS, XRS, XRL, TNEXT)                                        \
  {                                                                                  \
    f32x4 a0e = (f32x4){0.f,0.f,0.f,0.f}, a0o = a0e, a1e = a0e, a1o = a0e;           \
    __builtin_amdgcn_s_setprio(1);                                                   \
    _Pragma("unroll")                                                                \
    for (int kt = 0; kt < 10; kt += 2) {                                             \
      const s16x8 hbe = *(const s16x8*)(RD + kt * 32);                               \
      const s16x8 hbo = *(const s16x8*)(RD + (kt + 1) * 32);                         \
      a0e = __builtin_amdgcn_mfma_f32_16x16x32_bf16(waug[0][kt], hbe, a0e, 0, 0, 0); \
      a1e = __builtin_amdgcn_mfma_f32_16x16x32_bf16(waug[1][kt], hbe, a1e, 0, 0, 0); \
      a0o = __builtin_amdgcn_mfma_f32_16x16x32_bf16(waug[0][kt+1], hbo, a0o, 0, 0, 0);\
      a1o = __builtin_amdgcn_mfma_f32_16x16x32_bf16(waug[1][kt+1], hbo, a1o, 0, 0, 0);\
    }                                                                                \
    __builtin_amdgcn_s_setprio(0);                                                   \
    *(unsigned int*)(XS) = cvtpk2bf(XRS.x, XRS.y);  /* stage x_{t+1} */              \
    XRL = *(const float2*)(xrow + (TNEXT) * DIN);   /* prefetch */                   \
    _Pragma("unroll")                                                                \
    for (int rt = 0; rt < 2; ++rt) {                                                 \
      const f32x4 ae = rt ? a1e : a0e;                                               \
      const f32x4 ao = rt ? a1o : a0o;                                               \
      f32x4 hn;                                                                      \
      _Pragma("unroll")                                                              \
      for (int i = 0; i < 4; ++i) {                                                  \
        const float e = __builtin_amdgcn_exp2f(ae[i] + ao[i]);  /* W pre-scaled */   \
        const float rc = __builtin_amdgcn_rcpf(e + 1.0f);                            \
        hn[i] = fmaf(-0.6f, rc, fmaf(0.7f, hreg[rt][i], 0.3f));                      \
      }                                                                              \
      hreg[rt] = hn;                                                                 \
      *(uint2*)(WH + rt * 16) =                                                      \
          make_uint2(cvtpk2bf(hn[0], hn[1]), cvtpk2bf(hn[2], hn[3]));                \
    }                                                                                \
  }

  for (int tc = 0; tc < TT / 2; ++tc) {
    const int t = tc * 2;
    // half-step A: t even — read buf0, write h_{t+1} & x_{t+1} into buf1
    const int tla = (t + 3 < TT) ? t + 3 : TT - 1;
    ESN_STEP(rd0, wh1, xs1, xr1, xr1, tla);
    __syncthreads();
    // half-step B: t odd — read buf1, write into buf0
    const int tlb = (t + 4 < TT) ? t + 4 : TT - 1;
    ESN_STEP(rd1, wh0, xs0, xr0, xr0, tlb);
    __syncthreads();
  }
#undef ESN_STEP

  // final state -> cat[:, 0:256] fp16 + fp8 shadow slice 0
#pragma unroll
  for (int rt = 0; rt < 2; ++rt) {
    *(uint2*)(cat + (gn0 + lr) * CATD + w * 32 + rt * 16 + lg * 4) =
        make_uint2(pack2h(hreg[rt][0], hreg[rt][1]), pack2h(hreg[rt][2], hreg[rt][3]));
    *(unsigned int*)(cat8 + (gn0 + lr) * C8ROW + w * 32 + rt * 16 + lg * 4) =
        pack4fp8(hreg[rt][0], hreg[rt][1], hreg[rt][2], hreg[rt][3]);
  }
}

// ---------------- SpMV hops: fp8 gathers, 1 node/wave, 4 row-streams -----------
// out[n][r] = dinv[n] * sum_j dinv[j] * in8[j][r].
// Lane = s*16+p: stream s (0..3) walks neighbor rows; lane covers fp8 cols
// [p*16, p*16+16) = 16 B/gather, so one wave instruction gathers 4 rows.
// Branch-free fully-unrolled 16-iter chunk body: tail entries carry dv=0
// (zero contribution; dummy gathers hit row 0). Cross-stream shfl_xor reduce.
__global__ __launch_bounds__(256) void spmv_kernel(
    const unsigned short* __restrict__ nbrlist, const int* __restrict__ nbrcnt,
    const float* __restrict__ dinv, unsigned short* __restrict__ cat,
    unsigned char* __restrict__ cat8, int hop)
{
  const int wv   = threadIdx.x >> 6;     // wave 0..3
  const int lane = threadIdx.x & 63;
  const int s    = lane >> 4;            // row stream 0..3
  const int p    = lane & 15;            // col block
  const int n    = blockIdx.x * 4 + wv;
  const int cnt  = nbrcnt[n];
  const unsigned char* in8 = cat8 + (size_t)(hop - 1) * RR;   // + j*C8ROW
  float acc[16];
#pragma unroll
  for (int k = 0; k < 16; ++k) acc[k] = 0.0f;

  // chunk of 64 neighbors across all lanes; next chunk preloads before body
  int idx = 0; float dv = 0.f;
  if (lane < cnt) {
    idx = (int)nbrlist[(size_t)n * MAXD + lane];
    dv  = dinv[idx];
  }
  for (int c0 = 0; c0 < cnt; c0 += 64) {
    int idxn = 0; float dvn = 0.f;
    if (c0 + 64 + lane < cnt) {
      idxn = (int)nbrlist[(size_t)n * MAXD + c0 + 64 + lane];
      dvn  = dinv[idxn];
    }
#pragma unroll
    for (int i = 0; i < 16; ++i) {
      const int   j  = __shfl(idx, s * 16 + i, 64);
      const float wj = __shfl(dv,  s * 16 + i, 64);
      const uint4 u  = *(const uint4*)(in8 + (size_t)j * C8ROW + p * 16);
      const f32x2 v0 = __builtin_amdgcn_cvt_pk_f32_fp8((int)u.x, false);
      const f32x2 v1 = __builtin_amdgcn_cvt_pk_f32_fp8((int)u.x, true);
      const f32x2 v2 = __builtin_amdgcn_cvt_pk_f32_fp8((int)u.y, false);
      const f32x2 v3 = __builtin_amdgcn_cvt_pk_f32_fp8((int)u.y, true);
      const f32x2 v4 = __builtin_amdgcn_cvt_pk_f32_fp8((int)u.z, false);
      const f32x2 v5 = __builtin_amdgcn_cvt_pk_f32_fp8((int)u.z, true);
      const f32x2 v6 = __builtin_amdgcn_cvt_pk_f32_fp8((int)u.w, false);
      const f32x2 v7 = __builtin_amdgcn_cvt_pk_f32_fp8((int)u.w, true);
      acc[0]  += wj * v0[0]; acc[1]  += wj * v0[1];
      acc[2]  += wj * v1[0]; acc[3]  += wj * v1[1];
      acc[4]  += wj * v2[0]; acc[5]  += wj * v2[1];
      acc[6]  += wj * v3[0]; acc[7]  += wj * v3[1];
      acc[8]  += wj * v4[0]; acc[9]  += wj * v4[1];
      acc[10] += wj * v5[0]; acc[11] += wj * v5[1];
      acc[12] += wj * v6[0]; acc[13] += wj * v6[1];
      acc[14] += wj * v7[0]; acc[15] += wj * v7[1];
    }
    idx = idxn; dv = dvn;
  }
  // reduce the 4 streams (identical col mapping in all streams)
#pragma unroll
  for (int k = 0; k < 16; ++k) {
    acc[k] += __shfl_xor(acc[k], 16, 64);
    acc[k] += __shfl_xor(acc[k], 32, 64);
  }

  if (s == 0) {
    const float dn = dinv[n];
#pragma unroll
    for (int k = 0; k < 16; ++k) acc[k] *= dn;
    unsigned short* orow = cat + (size_t)n * CATD + (size_t)hop * RR + p * 16;
    uint4 o1, o2;
    o1.x = pack2h(acc[0],  acc[1]);  o1.y = pack2h(acc[2],  acc[3]);
    o1.z = pack2h(acc[4],  acc[5]);  o1.w = pack2h(acc[6],  acc[7]);
    o2.x = pack2h(acc[8],  acc[9]);  o2.y = pack2h(acc[10], acc[11]);
    o2.z = pack2h(acc[12], acc[13]); o2.w = pack2h(acc[14], acc[15]);
    *(uint4*)orow = o1;
    *(uint4*)(orow + 8) = o2;
    if (hop < 3) {
      uint4 o8;
      o8.x = pack4fp8(acc[0],  acc[1],  acc[2],  acc[3]);
      o8.y = pack4fp8(acc[4],  acc[5],  acc[6],  acc[7]);
      o8.z = pack4fp8(acc[8],  acc[9],  acc[10], acc[11]);
      o8.w = pack4fp8(acc[12], acc[13], acc[14], acc[15]);
      *(uint4*)(cat8 + (size_t)n * C8ROW + (size_t)hop * RR + p * 16) = o8;
    }
  }
}

// ---------------- fused readout: MFMA GEMM1 + GELU + GEMM2 + LayerNorm ----------------
// Block: 256 threads = 4 waves, 32 nodes (2 node-tiles share B-fragments) —
// minimal-redundancy form: each cat row and each W1h row read once per block.
__global__ __launch_bounds__(256) void readout_kernel(
    const unsigned short* __restrict__ cat,  // [N][1024] fp16
    const unsigned short* __restrict__ W1h,  // [128][1024] fp16
    const float* __restrict__ b1,
    const unsigned short* __restrict__ W2h,  // [64][128] fp16
    const float* __restrict__ b2, const float* __restrict__ gamma,
    const float* __restrict__ beta, float* __restrict__ out)
{
  __shared__ unsigned short z1[32][136];   // fp16, pad 136
  __shared__ float z2[32][68];
  const int tid  = threadIdx.x;
  const int lane = tid & 63;
  const int w    = tid >> 6;
  const int lr   = lane & 15;
  const int lg   = lane >> 4;
  const long gn0 = (long)blockIdx.x * 32;

  // GEMM1: D1[node][hid] = cat(32x1024) @ W1^T ; wave w -> hid tiles 2w, 2w+1
  f32x4 a00 = (f32x4){0.f,0.f,0.f,0.f}, a01 = a00, a10 = a00, a11 = a00;
  const unsigned short* arow0 = cat + (gn0 + lr) * CATD;
  const unsigned short* arow1 = cat + (gn0 + 16 + lr) * CATD;
  const unsigned short* brow0 = W1h + (w * 32 + lr) * CATD;
  const unsigned short* brow1 = W1h + (w * 32 + 16 + lr) * CATD;
#pragma unroll 8
  for (int kt = 0; kt < 32; ++kt) {
    const f16x8 af0 = *(const f16x8*)(arow0 + kt * 32 + lg * 8);
    const f16x8 af1 = *(const f16x8*)(arow1 + kt * 32 + lg * 8);
    const f16x8 bf0 = *(const f16x8*)(brow0 + kt * 32 + lg * 8);
    const f16x8 bf1 = *(const f16x8*)(brow1 + kt * 32 + lg * 8);
    a00 = __builtin_amdgcn_mfma_f32_16x16x32_f16(af0, bf0, a00, 0, 0, 0);
    a01 = __builtin_amdgcn_mfma_f32_16x16x32_f16(af0, bf1, a01, 0, 0, 0);
    a10 = __builtin_amdgcn_mfma_f32_16x16x32_f16(af1, bf0, a10, 0, 0, 0);
    a11 = __builtin_amdgcn_mfma_f32_16x16x32_f16(af1, bf1, a11, 0, 0, 0);
  }
  const float is2 = 0.70710678118654752f;
#pragma unroll
  for (int nt = 0; nt < 2; ++nt) {
#pragma unroll
    for (int ht = 0; ht < 2; ++ht) {
      const int hid = w * 32 + ht * 16 + lr;
      const float bb = b1[hid];
      const f32x4 a = nt ? (ht ? a11 : a10) : (ht ? a01 : a00);
#pragma unroll
      for (int i = 0; i < 4; ++i) {
        const float v = a[i] + bb;
        const float g = 0.5f * v * (1.0f + erff(v * is2));
        z1[nt * 16 + lg * 4 + i][hid] = __half_as_ushort(__float2half(g));
      }
    }
  }
  __syncthreads();

  // GEMM2: D2[node][o] = z1(32x128) @ W2^T ; wave w -> out tile w
  f32x4 c20 = (f32x4){0.f,0.f,0.f,0.f}, c21 = c20;
  const unsigned short* w2row = W2h + (w * 16 + lr) * HID;
#pragma unroll
  for (int kt = 0; kt < 4; ++kt) {
    const f16x8 bf  = *(const f16x8*)(w2row + kt * 32 + lg * 8);
    const f16x8 af0 = *(const f16x8*)(&z1[lr][kt * 32 + lg * 8]);
    const f16x8 af1 = *(const f16x8*)(&z1[16 + lr][kt * 32 + lg * 8]);
    c20 = __builtin_amdgcn_mfma_f32_16x16x32_f16(af0, bf, c20, 0, 0, 0);
    c21 = __builtin_amdgcn_mfma_f32_16x16x32_f16(af1, bf, c21, 0, 0, 0);
  }
  {
    const float bb = b2[w * 16 + lr];
#pragma unroll
    for (int i = 0; i < 4; ++i) {
      z2[lg * 4 + i][w * 16 + lr]      = c20[i] + bb;
      z2[16 + lg * 4 + i][w * 16 + lr] = c21[i] + bb;
    }
  }
  __syncthreads();

  // LayerNorm over 64 out-dims; 8 threads per node, 8 cols each
  {
    const int n = tid >> 3;
    const int c = tid & 7;
    float v[8], s = 0.0f, s2 = 0.0f;
#pragma unroll
    for (int k2 = 0; k2 < 8; ++k2) {
      v[k2] = z2[n][c + 8 * k2];
      s += v[k2]; s2 += v[k2] * v[k2];
    }
#pragma unroll
    for (int m = 1; m < 8; m <<= 1) {
      s  += __shfl_xor(s,  m, 64);
      s2 += __shfl_xor(s2, m, 64);
    }
    const float mu  = s * (1.0f / 64.0f);
    const float var = s2 * (1.0f / 64.0f) - mu * mu;
    const float inv = rsqrtf(var + 1e-5f);
    float* orow = out + (gn0 + n) * DOUT;
#pragma unroll
    for (int k2 = 0; k2 < 8; ++k2)
      orow[c + 8 * k2] = (v[k2] - mu) * inv * gamma[c + 8 * k2] + beta[c + 8 * k2];
  }
}

// ---------------- launch ----------------

extern "C" void kernel_launch(void* const* d_in, const int* in_sizes, int n_in,
                              void* d_out, int out_size, void* d_ws, size_t ws_size,
                              hipStream_t stream) {
  const float* x     = (const float*)d_in[0];
  const int*   eidx  = (const int*)d_in[1];
  const float* W_in  = (const float*)d_in[2];
  const float* W_res = (const float*)d_in[3];
  const float* W1    = (const float*)d_in[4];
  const float* b1    = (const float*)d_in[5];
  const float* W2    = (const float*)d_in[6];
  const float* b2    = (const float*)d_in[7];
  const float* gamma = (const float*)d_in[8];
  const float* beta  = (const float*)d_in[9];
  float* out = (float*)d_out;

  char* ws = (char*)d_ws;
  size_t off = 0;
  auto alloc = [&](size_t bytes) {
    void* p = ws + off;
    off += (bytes + 255) & ~(size_t)255;
    return p;
  };
  unsigned int*   mask    = (unsigned int*)  alloc((size_t)NN * MASKW * 4);  // 8 MB
  unsigned short* cat     = (unsigned short*)alloc((size_t)NN * CATD * 2);   // 16 MB
  unsigned char*  cat8    = (unsigned char*) alloc((size_t)NN * C8ROW);      // 6 MB
  unsigned short* nbrlist = (unsigned short*)alloc((size_t)NN * MAXD * 2);   // 4 MB
  int*            nbrcnt  = (int*)           alloc((size_t)NN * 4);
  float*          dinv    = (float*)         alloc((size_t)NN * 4);
  unsigned short* wresh   = (unsigned short*)alloc((size_t)RR * RR * 2);
  unsigned short* winh    = (unsigned short*)alloc((size_t)RR * DIN * 2);
  unsigned short* W1h     = (unsigned short*)alloc((size_t)HID * CATD * 2);
  unsigned short* W2h     = (unsigned short*)alloc((size_t)DOUT * HID * 2);

  setup_kernel<<<2048, 256, 0, stream>>>((uint4*)mask, W_res, W_in, W1, W2,
                                         wresh, winh, W1h, W2h);
  edge_kernel<<<NE / 256, 256, 0, stream>>>(eidx, mask);
  nbrlist_kernel<<<NN, 256, 0, stream>>>(mask, nbrlist, nbrcnt, dinv);

  esn_mfma_kernel<<<NN / 16, 512, 0, stream>>>(x, winh, wresh, cat, cat8);

  for (int k = 1; k <= 3; ++k)
    spmv_kernel<<<NN / 4, 256, 0, stream>>>(nbrlist, nbrcnt, dinv, cat, cat8, k);

  readout_kernel<<<NN / 32, 256, 0, stream>>>(cat, W1h, b1, W2h, b2, gamma, beta, out);
}

// Round 21
// 164.458 us; speedup vs baseline: 1.0333x; 1.0333x over previous
//
#include <hip/hip_runtime.h>
#include <hip/hip_bf16.h>
#include <hip/hip_fp16.h>
#include <math.h>

#define NN    8192
#define TT    64
#define DIN   64
#define RR    256
#define DOUT  64
#define HID   128
#define CATD  1024
#define NE    131072
#define MASKW 256              // 8192 bits / 32
#define MAXD  256              // neighbor list capacity (avg deg ~32)
#define HROW  328              // shorts/node-row: 320 data (40 16B-slots) + 8 pad
#define C8ROW 768              // fp8 shadow row: 3 slices x 256 bytes
#define L2E2  2.8853900817779268f   // 2*log2(e), folded into W_aug at setup

typedef __attribute__((ext_vector_type(8))) short    s16x8;   // 8 bf16 bits
typedef __attribute__((ext_vector_type(8))) _Float16 f16x8;   // 8 fp16
typedef __attribute__((ext_vector_type(4))) float    f32x4;
typedef __attribute__((ext_vector_type(2))) float    f32x2;

static __device__ __forceinline__ unsigned short f2bs(float f) {
  union { __hip_bfloat16 b; unsigned short u; } cv;
  cv.b = __float2bfloat16(f);
  return cv.u;
}
static __device__ __forceinline__ unsigned int pack2bf(float a, float b) {
  return (unsigned int)f2bs(a) | ((unsigned int)f2bs(b) << 16);
}
// 1-inst packed f32->bf16 (RNE); safe for finite inputs (tanh outputs, x values)
static __device__ __forceinline__ unsigned int cvtpk2bf(float a, float b) {
  unsigned int r;
  asm("v_cvt_pk_bf16_f32 %0, %1, %2" : "=v"(r) : "v"(a), "v"(b));
  return r;
}
static __device__ __forceinline__ unsigned int pack2h(float a, float b) {
  return (unsigned int)__half_as_ushort(__float2half(a))
       | ((unsigned int)__half_as_ushort(__float2half(b)) << 16);
}
static __device__ __forceinline__ unsigned int pack4fp8(float a, float b, float c, float d) {
  unsigned int p = 0;
  p = __builtin_amdgcn_cvt_pk_fp8_f32(a, b, (int)p, false);   // bytes 0,1
  p = __builtin_amdgcn_cvt_pk_fp8_f32(c, d, (int)p, true);    // bytes 2,3
  return p;
}

// ---------------- setup kernels ----------------

// fused: zero adjacency mask + one-shot weight conversion
// W_res/W_in are pre-scaled by 2*log2(e) so the esn tanh needs no pre-multiply.
__global__ __launch_bounds__(256) void setup_kernel(
    uint4* __restrict__ mask4,
    const float* __restrict__ Wres, const float* __restrict__ Win,
    const float* __restrict__ W1, const float* __restrict__ W2,
    unsigned short* __restrict__ wresh, unsigned short* __restrict__ winh,
    unsigned short* __restrict__ W1h, unsigned short* __restrict__ W2h) {
  int i = blockIdx.x * 256 + threadIdx.x;
  mask4[i] = make_uint4(0u, 0u, 0u, 0u);       // grid exactly covers 8 MB / 16 B
  if (i < 65536) wresh[i] = f2bs(Wres[i] * L2E2);
  else if (i < 81920) winh[i - 65536] = f2bs(Win[i - 65536] * L2E2);
  else if (i < 212992) W1h[i - 81920] = __half_as_ushort(__float2half(W1[i - 81920]));
  else if (i < 221184) W2h[i - 212992] = __half_as_ushort(__float2half(W2[i - 212992]));
}

__global__ __launch_bounds__(256) void edge_kernel(const int* __restrict__ eidx,
                                                   unsigned int* __restrict__ mask) {
  int e = blockIdx.x * 256 + threadIdx.x;
  if (e < NE) {
    int u = eidx[e];
    int v = eidx[NE + e];
    atomicOr(&mask[(size_t)u * MASKW + (v >> 5)], 1u << (v & 31));
    atomicOr(&mask[(size_t)v * MASKW + (u >> 5)], 1u << (u & 31));
  }
}

// neighbor list via prefix scan over mask words; also emits dinv
__global__ __launch_bounds__(256) void nbrlist_kernel(const unsigned int* __restrict__ mask,
                                                      unsigned short* __restrict__ nbrlist,
                                                      int* __restrict__ nbrcnt,
                                                      float* __restrict__ dinv) {
  __shared__ int wsum[4];
  const int n = blockIdx.x;
  const int tid = threadIdx.x;
  const int lane = tid & 63;
  const int w = tid >> 6;
  unsigned int m = mask[(size_t)n * MASKW + tid];
  const int c = __popc(m);
  int inc = c;
#pragma unroll
  for (int d = 1; d < 64; d <<= 1) {
    int v = __shfl_up(inc, d, 64);
    if (lane >= d) inc += v;
  }
  if (lane == 63) wsum[w] = inc;
  __syncthreads();
  int base = 0;
  for (int i = 0; i < w; ++i) base += wsum[i];
  int off = base + inc - c;     // exclusive prefix
  while (m) {
    int b = __ffs(m) - 1;
    m &= m - 1;
    if (off < MAXD) nbrlist[(size_t)n * MAXD + off] = (unsigned short)(tid * 32 + b);
    ++off;
  }
  if (tid == 255) {
    int tot = base + inc;
    nbrcnt[n] = tot < MAXD ? tot : MAXD;
    dinv[n] = (tot > 0) ? fminf(rsqrtf((float)tot), 1e6f) : 0.0f;
  }
}

// ---------------- ESN via bf16 MFMA, augmented K=320 ----------------
// Block: 512 threads = 8 waves, 16 nodes. Wave w owns r in [w*32, w*32+32) (2 rtiles).
// A = W_aug rows (stationary, pre-scaled by 2*log2e), B = [h ; x_t] from LDS.
// Loop-invariant addressing, t-loop unrolled x2 for buffer ping-pong. 2 acc chains.
__global__ __launch_bounds__(512, 4) void esn_mfma_kernel(
    const float* __restrict__ x,               // [N][T][DIN] fp32
    const unsigned short* __restrict__ winh,   // [R][DIN] bf16 (pre-scaled)
    const unsigned short* __restrict__ wresh,  // [R][R]   bf16 (pre-scaled)
    unsigned short* __restrict__ cat,          // [N][CATD] fp16, writes cols 0..255
    unsigned char* __restrict__ cat8)          // [N][768] fp8 shadow, writes slice 0
{
  __shared__ unsigned short hs[2][16][HROW];   // [buf][node][k: 0..255 h, 256..319 x]
  const int tid  = threadIdx.x;
  const int lane = tid & 63;
  const int w    = tid >> 6;     // wave 0..7
  const int lr   = lane & 15;    // node (B col / D col)
  const int lg   = lane >> 4;    // k-group / row-group
  const int sn   = tid >> 5;     // staging: node 0..15
  const int sq   = tid & 31;     // staging: float2 index 0..31 (d = sq*2)
  const long gn0 = (long)blockIdx.x * 16;
  const int bx   = (lr >> 3) & 1;
  const int lgx  = lg ^ bx;              // read swizzle folded
  const int lgw  = (lg >> 1) ^ bx;       // write swizzle folded
  const int bs   = (sn >> 3) & 1;

  // stationary A-fragments: W_aug = [W_res | W_in], 2 rtiles x 10 ktiles
  s16x8 waug[2][10];
#pragma unroll
  for (int rt = 0; rt < 2; ++rt) {
    const int r = w * 32 + rt * 16 + lr;
#pragma unroll
    for (int kt = 0; kt < 8; ++kt)
      waug[rt][kt] = *(const s16x8*)(wresh + r * RR + kt * 32 + lg * 8);
#pragma unroll
    for (int kt = 8; kt < 10; ++kt)
      waug[rt][kt] = *(const s16x8*)(winh + r * DIN + (kt - 8) * 32 + lg * 8);
  }

  // loop-invariant LDS addresses (shorts)
  unsigned short* const rd0 = &hs[0][0][0] + lr * HROW + lgx * 8;  // + kt*32
  unsigned short* const rd1 = &hs[1][0][0] + lr * HROW + lgx * 8;
  unsigned short* const wh0 = &hs[0][0][0] + lr * HROW + (w * 4 + lgw) * 8 + (lg & 1) * 4;  // + rt*16
  unsigned short* const wh1 = &hs[1][0][0] + lr * HROW + (w * 4 + lgw) * 8 + (lg & 1) * 4;
  unsigned short* const xs0 = &hs[0][0][0] + sn * HROW + (32 + ((sq >> 2) ^ bs)) * 8 + (sq & 3) * 2;
  unsigned short* const xs1 = &hs[1][0][0] + sn * HROW + (32 + ((sq >> 2) ^ bs)) * 8 + (sq & 3) * 2;

  // zero buffer 0
  for (int i = tid; i < 16 * HROW / 2; i += 512) ((unsigned int*)hs[0])[i] = 0u;

  // rolling x prefetch: thread (sn, sq) loads float2
  const float* xrow = x + (gn0 + sn) * (long)(TT * DIN) + sq * 2;
  float2 xr0 = *(const float2*)(xrow);            // t=0
  float2 xr1 = *(const float2*)(xrow + DIN);      // t=1
  __syncthreads();                                // zeroing done
  *(unsigned int*)xs0 = cvtpk2bf(xr0.x, xr0.y);   // stage x_0 -> buf0
  xr0 = *(const float2*)(xrow + 2 * DIN);         // t=2

  f32x4 hreg[2];
  hreg[0] = (f32x4){0.f, 0.f, 0.f, 0.f};
  hreg[1] = (f32x4){0.f, 0.f, 0.f, 0.f};
  __syncthreads();

#define ESN_STEP(RD, WH, XS, XRS, XRL, TNEXT)                                        \
  {                                                                                  \
    f32x4 a0 = (f32x4){0.f,0.f,0.f,0.f}, a1 = a0;                                    \
    __builtin_amdgcn_s_setprio(1);                                                   \
    _Pragma("unroll")                                                                \
    for (int kt = 0; kt < 10; ++kt) {                                                \
      const s16x8 hb = *(const s16x8*)(RD + kt * 32);                                \
      a0 = __builtin_amdgcn_mfma_f32_16x16x32_bf16(waug[0][kt], hb, a0, 0, 0, 0);    \
      a1 = __builtin_amdgcn_mfma_f32_16x16x32_bf16(waug[1][kt], hb, a1, 0, 0, 0);    \
    }                                                                                \
    __builtin_amdgcn_s_setprio(0);                                                   \
    *(unsigned int*)(XS) = cvtpk2bf(XRS.x, XRS.y);  /* stage x_{t+1} */              \
    XRL = *(const float2*)(xrow + (TNEXT) * DIN);   /* prefetch */                   \
    _Pragma("unroll")                                                                \
    for (int rt = 0; rt < 2; ++rt) {                                                 \
      const f32x4 ae = rt ? a1 : a0;                                                 \
      f32x4 hn;                                                                      \
      _Pragma("unroll")                                                              \
      for (int i = 0; i < 4; ++i) {                                                  \
        const float e = __builtin_amdgcn_exp2f(ae[i]);   /* W pre-scaled */          \
        const float rc = __builtin_amdgcn_rcpf(e + 1.0f);                            \
        hn[i] = fmaf(-0.6f, rc, fmaf(0.7f, hreg[rt][i], 0.3f));                      \
      }                                                                              \
      hreg[rt] = hn;                                                                 \
      *(uint2*)(WH + rt * 16) =                                                      \
          make_uint2(cvtpk2bf(hn[0], hn[1]), cvtpk2bf(hn[2], hn[3]));                \
    }                                                                                \
  }

  for (int tc = 0; tc < TT / 2; ++tc) {
    const int t = tc * 2;
    // half-step A: t even — read buf0, write h_{t+1} & x_{t+1} into buf1
    const int tla = (t + 3 < TT) ? t + 3 : TT - 1;
    ESN_STEP(rd0, wh1, xs1, xr1, xr1, tla);
    __syncthreads();
    // half-step B: t odd — read buf1, write into buf0
    const int tlb = (t + 4 < TT) ? t + 4 : TT - 1;
    ESN_STEP(rd1, wh0, xs0, xr0, xr0, tlb);
    __syncthreads();
  }
#undef ESN_STEP

  // final state -> cat[:, 0:256] fp16 + fp8 shadow slice 0
#pragma unroll
  for (int rt = 0; rt < 2; ++rt) {
    *(uint2*)(cat + (gn0 + lr) * CATD + w * 32 + rt * 16 + lg * 4) =
        make_uint2(pack2h(hreg[rt][0], hreg[rt][1]), pack2h(hreg[rt][2], hreg[rt][3]));
    *(unsigned int*)(cat8 + (gn0 + lr) * C8ROW + w * 32 + rt * 16 + lg * 4) =
        pack4fp8(hreg[rt][0], hreg[rt][1], hreg[rt][2], hreg[rt][3]);
  }
}

// ---------------- SpMV hops: fp8 gathers, 1 node/wave, 4 row-streams -----------
// out[n][r] = dinv[n] * sum_j dinv[j] * in8[j][r].
// Lane = s*16+p: stream s (0..3) walks neighbor rows; lane covers fp8 cols
// [p*16, p*16+16) = 16 B/gather, so one wave instruction gathers 4 rows.
// Branch-free fully-unrolled 16-iter chunk body: tail entries carry dv=0
// (zero contribution; dummy gathers hit row 0). Cross-stream shfl_xor reduce.
__global__ __launch_bounds__(256) void spmv_kernel(
    const unsigned short* __restrict__ nbrlist, const int* __restrict__ nbrcnt,
    const float* __restrict__ dinv, unsigned short* __restrict__ cat,
    unsigned char* __restrict__ cat8, int hop)
{
  const int wv   = threadIdx.x >> 6;     // wave 0..3
  const int lane = threadIdx.x & 63;
  const int s    = lane >> 4;            // row stream 0..3
  const int p    = lane & 15;            // col block
  const int n    = blockIdx.x * 4 + wv;
  const int cnt  = nbrcnt[n];
  const unsigned char* in8 = cat8 + (size_t)(hop - 1) * RR;   // + j*C8ROW
  float acc[16];
#pragma unroll
  for (int k = 0; k < 16; ++k) acc[k] = 0.0f;

  // chunk of 64 neighbors across all lanes; next chunk preloads before body
  int idx = 0; float dv = 0.f;
  if (lane < cnt) {
    idx = (int)nbrlist[(size_t)n * MAXD + lane];
    dv  = dinv[idx];
  }
  for (int c0 = 0; c0 < cnt; c0 += 64) {
    int idxn = 0; float dvn = 0.f;
    if (c0 + 64 + lane < cnt) {
      idxn = (int)nbrlist[(size_t)n * MAXD + c0 + 64 + lane];
      dvn  = dinv[idxn];
    }
#pragma unroll
    for (int i = 0; i < 16; ++i) {
      const int   j  = __shfl(idx, s * 16 + i, 64);
      const float wj = __shfl(dv,  s * 16 + i, 64);
      const uint4 u  = *(const uint4*)(in8 + (size_t)j * C8ROW + p * 16);
      const f32x2 v0 = __builtin_amdgcn_cvt_pk_f32_fp8((int)u.x, false);
      const f32x2 v1 = __builtin_amdgcn_cvt_pk_f32_fp8((int)u.x, true);
      const f32x2 v2 = __builtin_amdgcn_cvt_pk_f32_fp8((int)u.y, false);
      const f32x2 v3 = __builtin_amdgcn_cvt_pk_f32_fp8((int)u.y, true);
      const f32x2 v4 = __builtin_amdgcn_cvt_pk_f32_fp8((int)u.z, false);
      const f32x2 v5 = __builtin_amdgcn_cvt_pk_f32_fp8((int)u.z, true);
      const f32x2 v6 = __builtin_amdgcn_cvt_pk_f32_fp8((int)u.w, false);
      const f32x2 v7 = __builtin_amdgcn_cvt_pk_f32_fp8((int)u.w, true);
      acc[0]  += wj * v0[0]; acc[1]  += wj * v0[1];
      acc[2]  += wj * v1[0]; acc[3]  += wj * v1[1];
      acc[4]  += wj * v2[0]; acc[5]  += wj * v2[1];
      acc[6]  += wj * v3[0]; acc[7]  += wj * v3[1];
      acc[8]  += wj * v4[0]; acc[9]  += wj * v4[1];
      acc[10] += wj * v5[0]; acc[11] += wj * v5[1];
      acc[12] += wj * v6[0]; acc[13] += wj * v6[1];
      acc[14] += wj * v7[0]; acc[15] += wj * v7[1];
    }
    idx = idxn; dv = dvn;
  }
  // reduce the 4 streams (identical col mapping in all streams)
#pragma unroll
  for (int k = 0; k < 16; ++k) {
    acc[k] += __shfl_xor(acc[k], 16, 64);
    acc[k] += __shfl_xor(acc[k], 32, 64);
  }

  if (s == 0) {
    const float dn = dinv[n];
#pragma unroll
    for (int k = 0; k < 16; ++k) acc[k] *= dn;
    unsigned short* orow = cat + (size_t)n * CATD + (size_t)hop * RR + p * 16;
    uint4 o1, o2;
    o1.x = pack2h(acc[0],  acc[1]);  o1.y = pack2h(acc[2],  acc[3]);
    o1.z = pack2h(acc[4],  acc[5]);  o1.w = pack2h(acc[6],  acc[7]);
    o2.x = pack2h(acc[8],  acc[9]);  o2.y = pack2h(acc[10], acc[11]);
    o2.z = pack2h(acc[12], acc[13]); o2.w = pack2h(acc[14], acc[15]);
    *(uint4*)orow = o1;
    *(uint4*)(orow + 8) = o2;
    if (hop < 3) {
      uint4 o8;
      o8.x = pack4fp8(acc[0],  acc[1],  acc[2],  acc[3]);
      o8.y = pack4fp8(acc[4],  acc[5],  acc[6],  acc[7]);
      o8.z = pack4fp8(acc[8],  acc[9],  acc[10], acc[11]);
      o8.w = pack4fp8(acc[12], acc[13], acc[14], acc[15]);
      *(uint4*)(cat8 + (size_t)n * C8ROW + (size_t)hop * RR + p * 16) = o8;
    }
  }
}

// ---------------- fused readout: MFMA GEMM1 + GELU + GEMM2 + LayerNorm ----------------
// Block: 256 threads = 4 waves, 32 nodes (2 node-tiles share B-fragments) —
// minimal-redundancy form: each cat row and each W1h row read once per block.
__global__ __launch_bounds__(256) void readout_kernel(
    const unsigned short* __restrict__ cat,  // [N][1024] fp16
    const unsigned short* __restrict__ W1h,  // [128][1024] fp16
    const float* __restrict__ b1,
    const unsigned short* __restrict__ W2h,  // [64][128] fp16
    const float* __restrict__ b2, const float* __restrict__ gamma,
    const float* __restrict__ beta, float* __restrict__ out)
{
  __shared__ unsigned short z1[32][136];   // fp16, pad 136
  __shared__ float z2[32][68];
  const int tid  = threadIdx.x;
  const int lane = tid & 63;
  const int w    = tid >> 6;
  const int lr   = lane & 15;
  const int lg   = lane >> 4;
  const long gn0 = (long)blockIdx.x * 32;

  // GEMM1: D1[node][hid] = cat(32x1024) @ W1^T ; wave w -> hid tiles 2w, 2w+1
  f32x4 a00 = (f32x4){0.f,0.f,0.f,0.f}, a01 = a00, a10 = a00, a11 = a00;
  const unsigned short* arow0 = cat + (gn0 + lr) * CATD;
  const unsigned short* arow1 = cat + (gn0 + 16 + lr) * CATD;
  const unsigned short* brow0 = W1h + (w * 32 + lr) * CATD;
  const unsigned short* brow1 = W1h + (w * 32 + 16 + lr) * CATD;
#pragma unroll 8
  for (int kt = 0; kt < 32; ++kt) {
    const f16x8 af0 = *(const f16x8*)(arow0 + kt * 32 + lg * 8);
    const f16x8 af1 = *(const f16x8*)(arow1 + kt * 32 + lg * 8);
    const f16x8 bf0 = *(const f16x8*)(brow0 + kt * 32 + lg * 8);
    const f16x8 bf1 = *(const f16x8*)(brow1 + kt * 32 + lg * 8);
    a00 = __builtin_amdgcn_mfma_f32_16x16x32_f16(af0, bf0, a00, 0, 0, 0);
    a01 = __builtin_amdgcn_mfma_f32_16x16x32_f16(af0, bf1, a01, 0, 0, 0);
    a10 = __builtin_amdgcn_mfma_f32_16x16x32_f16(af1, bf0, a10, 0, 0, 0);
    a11 = __builtin_amdgcn_mfma_f32_16x16x32_f16(af1, bf1, a11, 0, 0, 0);
  }
  const float is2 = 0.70710678118654752f;
#pragma unroll
  for (int nt = 0; nt < 2; ++nt) {
#pragma unroll
    for (int ht = 0; ht < 2; ++ht) {
      const int hid = w * 32 + ht * 16 + lr;
      const float bb = b1[hid];
      const f32x4 a = nt ? (ht ? a11 : a10) : (ht ? a01 : a00);
#pragma unroll
      for (int i = 0; i < 4; ++i) {
        const float v = a[i] + bb;
        const float g = 0.5f * v * (1.0f + erff(v * is2));
        z1[nt * 16 + lg * 4 + i][hid] = __half_as_ushort(__float2half(g));
      }
    }
  }
  __syncthreads();

  // GEMM2: D2[node][o] = z1(32x128) @ W2^T ; wave w -> out tile w
  f32x4 c20 = (f32x4){0.f,0.f,0.f,0.f}, c21 = c20;
  const unsigned short* w2row = W2h + (w * 16 + lr) * HID;
#pragma unroll
  for (int kt = 0; kt < 4; ++kt) {
    const f16x8 bf  = *(const f16x8*)(w2row + kt * 32 + lg * 8);
    const f16x8 af0 = *(const f16x8*)(&z1[lr][kt * 32 + lg * 8]);
    const f16x8 af1 = *(const f16x8*)(&z1[16 + lr][kt * 32 + lg * 8]);
    c20 = __builtin_amdgcn_mfma_f32_16x16x32_f16(af0, bf, c20, 0, 0, 0);
    c21 = __builtin_amdgcn_mfma_f32_16x16x32_f16(af1, bf, c21, 0, 0, 0);
  }
  {
    const float bb = b2[w * 16 + lr];
#pragma unroll
    for (int i = 0; i < 4; ++i) {
      z2[lg * 4 + i][w * 16 + lr]      = c20[i] + bb;
      z2[16 + lg * 4 + i][w * 16 + lr] = c21[i] + bb;
    }
  }
  __syncthreads();

  // LayerNorm over 64 out-dims; 8 threads per node, 8 cols each
  {
    const int n = tid >> 3;
    const int c = tid & 7;
    float v[8], s = 0.0f, s2 = 0.0f;
#pragma unroll
    for (int k2 = 0; k2 < 8; ++k2) {
      v[k2] = z2[n][c + 8 * k2];
      s += v[k2]; s2 += v[k2] * v[k2];
    }
#pragma unroll
    for (int m = 1; m < 8; m <<= 1) {
      s  += __shfl_xor(s,  m, 64);
      s2 += __shfl_xor(s2, m, 64);
    }
    const float mu  = s * (1.0f / 64.0f);
    const float var = s2 * (1.0f / 64.0f) - mu * mu;
    const float inv = rsqrtf(var + 1e-5f);
    float* orow = out + (gn0 + n) * DOUT;
#pragma unroll
    for (int k2 = 0; k2 < 8; ++k2)
      orow[c + 8 * k2] = (v[k2] - mu) * inv * gamma[c + 8 * k2] + beta[c + 8 * k2];
  }
}

// ---------------- launch ----------------

extern "C" void kernel_launch(void* const* d_in, const int* in_sizes, int n_in,
                              void* d_out, int out_size, void* d_ws, size_t ws_size,
                              hipStream_t stream) {
  const float* x     = (const float*)d_in[0];
  const int*   eidx  = (const int*)d_in[1];
  const float* W_in  = (const float*)d_in[2];
  const float* W_res = (const float*)d_in[3];
  const float* W1    = (const float*)d_in[4];
  const float* b1    = (const float*)d_in[5];
  const float* W2    = (const float*)d_in[6];
  const float* b2    = (const float*)d_in[7];
  const float* gamma = (const float*)d_in[8];
  const float* beta  = (const float*)d_in[9];
  float* out = (float*)d_out;

  char* ws = (char*)d_ws;
  size_t off = 0;
  auto alloc = [&](size_t bytes) {
    void* p = ws + off;
    off += (bytes + 255) & ~(size_t)255;
    return p;
  };
  unsigned int*   mask    = (unsigned int*)  alloc((size_t)NN * MASKW * 4);  // 8 MB
  unsigned short* cat     = (unsigned short*)alloc((size_t)NN * CATD * 2);   // 16 MB
  unsigned char*  cat8    = (unsigned char*) alloc((size_t)NN * C8ROW);      // 6 MB
  unsigned short* nbrlist = (unsigned short*)alloc((size_t)NN * MAXD * 2);   // 4 MB
  int*            nbrcnt  = (int*)           alloc((size_t)NN * 4);
  float*          dinv    = (float*)         alloc((size_t)NN * 4);
  unsigned short* wresh   = (unsigned short*)alloc((size_t)RR * RR * 2);
  unsigned short* winh    = (unsigned short*)alloc((size_t)RR * DIN * 2);
  unsigned short* W1h     = (unsigned short*)alloc((size_t)HID * CATD * 2);
  unsigned short* W2h     = (unsigned short*)alloc((size_t)DOUT * HID * 2);

  setup_kernel<<<2048, 256, 0, stream>>>((uint4*)mask, W_res, W_in, W1, W2,
                                         wresh, winh, W1h, W2h);
  edge_kernel<<<NE / 256, 256, 0, stream>>>(eidx, mask);
  nbrlist_kernel<<<NN, 256, 0, stream>>>(mask, nbrlist, nbrcnt, dinv);

  esn_mfma_kernel<<<NN / 16, 512, 0, stream>>>(x, winh, wresh, cat, cat8);

  for (int k = 1; k <= 3; ++k)
    spmv_kernel<<<NN / 4, 256, 0, stream>>>(nbrlist, nbrcnt, dinv, cat, cat8, k);

  readout_kernel<<<NN / 32, 256, 0, stream>>>(cat, W1h, b1, W2h, b2, gamma, beta, out);
}